// Round 10
// baseline (52.172 us; speedup 1.0000x reference)
//
#include <hip/hip_runtime.h>
#include <hip/hip_fp16.h>

#define MARGIN 0.2f
#define WINDOW 0.25f     // compact |s| < WINDOW in pass 1
#define MU_MAX 0.045     // fast path valid iff |mean| <= MU_MAX (WINDOW - MU_MAX > MARGIN)
#define NBLK 2048        // K1 grid (unchanged from R8)
#define NB2  512         // K2 fast-path grid: each block owns 4 K1 blocks' segments
#define NTHR 256
#define WPB  (NTHR / 64) // waves per block
#define WCAP 1280        // per-wave candidate capacity (expected ~809, sigma ~26)
#define K1_PER_K2 (NBLK / NB2)   // 4: K1-chunks (and segs/wave) per K2 block

// Lessons (R3-R5,R9): NO mid-kernel __threadfence (~+220us), NO fused finalize
// via same-line atomics (~+35us), NO histogram re-attempt (unexplained
// post-timing divergence in R9). Kernel boundaries are the cheap cross-block
// barrier; ballot-compaction is bit-deterministic (no atomics).
// R8 base: half-packed candidates (all in (-0.25,0.25), ulp <= 1.22e-4;
// final-mean error bound ~1.2e-5 << 3.17e-4 threshold).
// R10 delta: K2 fast grid 512 (4 segments per wave) -> p1 broadcast 33->8 MB.
struct Ws {
    double   p1[NBLK];                        // per-block partial sums
    double   p2[NBLK];                        // per-block partial loss sums
    unsigned counts[NBLK * WPB];              // true per-wave candidate counts
    __half   cand[(size_t)NBLK * WPB * WCAP]; // per-wave candidate segments (~21 MB)
};

__device__ __forceinline__ double block_reduce(double v, double* lds) {
    #pragma unroll
    for (int off = 32; off > 0; off >>= 1) v += __shfl_down(v, off);
    const int w = threadIdx.x >> 6;
    if ((threadIdx.x & 63) == 0) lds[w] = v;
    __syncthreads();
    double t = 0.0;
    if (threadIdx.x == 0) {
        #pragma unroll
        for (int i = 0; i < WPB; ++i) t += lds[i];
    }
    __syncthreads();
    return t;
}

// Contiguous chunk geometry over NBLK chunks: chunk b owns len4 float4s at base4.
__device__ __forceinline__ void chunk_of(long n4, long b, long& base4, long& len4) {
    const long chunk4 = n4 / NBLK, rem4 = n4 % NBLK;
    base4 = b * chunk4 + (b < rem4 ? b : rem4);
    len4  = chunk4 + (b < rem4 ? 1 : 0);
}

// ---------------------------------------------------------------------------
// Kernel A (byte-identical to R8): per-block sum; if COMPACT, wave-ballot-
// compact |s|<WINDOW candidates (as __half) into fixed per-wave segments.
// ---------------------------------------------------------------------------
template<bool COMPACT>
__global__ __launch_bounds__(NTHR) void sum_kernel(
    const float* __restrict__ in, long n, Ws* __restrict__ ws) {
    __shared__ double lds[WPB];
    const long n4 = n >> 2;
    const float4* __restrict__ in4 = reinterpret_cast<const float4*>(in);
    long base4, len4;
    chunk_of(n4, blockIdx.x, base4, len4);
    const int tid = threadIdx.x;
    const unsigned lane =
        __builtin_amdgcn_mbcnt_hi(~0u, __builtin_amdgcn_mbcnt_lo(~0u, 0u));
    const unsigned long long below = (1ull << lane) - 1ull;

    __half* seg = nullptr;
    unsigned wbase = 0;
    if (COMPACT)
        seg = ws->cand + (size_t)(blockIdx.x * WPB + (tid >> 6)) * WCAP;

    float s = 0.0f;
    const long rounds = (len4 + NTHR - 1) / NTHR;   // wave-uniform trip count
    for (long r = 0; r < rounds; ++r) {
        const long k = r * NTHR + tid;
        const bool act = (k < len4);
        float4 v = act ? in4[base4 + k] : make_float4(0.f, 0.f, 0.f, 0.f);
        if (COMPACT) {
            const float e[4] = {v.x, v.y, v.z, v.w};
            #pragma unroll
            for (int c = 0; c < 4; ++c) {
                const bool cand = act && (fabsf(e[c]) < WINDOW);
                const unsigned long long m = __ballot(cand);
                if (cand) {
                    const unsigned off = wbase + (unsigned)__popcll(m & below);
                    if (off < WCAP) seg[off] = __float2half(e[c]);
                }
                wbase += (unsigned)__popcll(m);
            }
        }
        s += (v.x + v.y) + (v.z + v.w);
    }
    if (COMPACT && (tid & 63) == 0)
        ws->counts[blockIdx.x * WPB + (tid >> 6)] = wbase;  // TRUE count

    if (blockIdx.x == 0) {   // scalar tail (n % 4)
        for (long j = (n4 << 2) + tid; j < n; j += NTHR) s += in[j];
    }
    const double t = block_reduce((double)s, lds);
    if (tid == 0) ws->p1[blockIdx.x] = t;
}

// ---------------------------------------------------------------------------
// Kernel B: mean from p1, then loss.
// TRY_FAST (grid = NB2): each block owns the 16 segments of K1 blocks
// [blockIdx*4 .. blockIdx*4+3]; each wave walks 4 segments. Fallbacks
// (|mean|>MU_MAX grid-wide, or any owned segment overflowed) rescan exactly
// those 4 K1 chunks. Exactness of exclusion: |s| >= WINDOW and
// |mean| <= MU_MAX -> |s-mean| >= 0.205 > MARGIN -> loss exactly 0.
// !TRY_FAST (grid = NBLK): classic full rescan of own chunk.
// ---------------------------------------------------------------------------
template<bool TRY_FAST>
__global__ __launch_bounds__(NTHR) void loss_kernel(
    const float* __restrict__ in, long n, Ws* __restrict__ ws) {
    __shared__ double lds[WPB];
    const int tid = threadIdx.x;

    double m = 0.0;
    for (int k = tid; k < NBLK; k += NTHR) m += ws->p1[k];
    m = block_reduce(m, lds);
    __shared__ double s_mean;
    if (tid == 0) s_mean = m / (double)n;
    __syncthreads();
    const float mean = (float)s_mean;

    const long n4 = n >> 2;
    const float4* __restrict__ in4 = reinterpret_cast<const float4*>(in);

    float s = 0.0f;
    if (TRY_FAST) {
        __shared__ int s_ovf;
        if (tid == 0) {
            int of = 0;
            #pragma unroll
            for (int q = 0; q < WPB * K1_PER_K2; ++q)
                of |= (ws->counts[blockIdx.x * WPB * K1_PER_K2 + q] > WCAP) ? 1 : 0;
            s_ovf = of;
        }
        __syncthreads();
        const bool fast = (fabs(s_mean) <= (double)MU_MAX) && (s_ovf == 0);

        if (fast) {
            const int wave = tid >> 6, lane = tid & 63;
            const unsigned wave_gid = blockIdx.x * WPB + wave;
            #pragma unroll
            for (int g = 0; g < K1_PER_K2; ++g) {
                const unsigned sid = wave_gid * K1_PER_K2 + g;
                const unsigned cnt = ws->counts[sid];
                const __half* __restrict__ seg = ws->cand + (size_t)sid * WCAP;
                for (unsigned j = lane; j < cnt; j += 64)
                    s += fmaxf(MARGIN - fabsf(__half2float(seg[j]) - mean), 0.0f);
            }
        } else {
            // rescan exactly the 4 K1 chunks this block owns
            for (int g = 0; g < K1_PER_K2; ++g) {
                long base4, len4;
                chunk_of(n4, (long)blockIdx.x * K1_PER_K2 + g, base4, len4);
                for (long k = tid; k < len4; k += NTHR) {
                    float4 v = in4[base4 + k];
                    s += fmaxf(MARGIN - fabsf(v.x - mean), 0.0f)
                       + fmaxf(MARGIN - fabsf(v.y - mean), 0.0f);
                    s += fmaxf(MARGIN - fabsf(v.z - mean), 0.0f)
                       + fmaxf(MARGIN - fabsf(v.w - mean), 0.0f);
                }
            }
        }
    } else {
        long base4, len4;
        chunk_of(n4, blockIdx.x, base4, len4);
        for (long k = tid; k < len4; k += NTHR) {
            float4 v = in4[base4 + k];
            s += fmaxf(MARGIN - fabsf(v.x - mean), 0.0f)
               + fmaxf(MARGIN - fabsf(v.y - mean), 0.0f);
            s += fmaxf(MARGIN - fabsf(v.z - mean), 0.0f)
               + fmaxf(MARGIN - fabsf(v.w - mean), 0.0f);
        }
    }
    if (blockIdx.x == 0) {   // scalar tail (n % 4)
        for (long j = (n4 << 2) + tid; j < n; j += NTHR)
            s += fmaxf(MARGIN - fabsf(in[j] - mean), 0.0f);
    }
    const double t = block_reduce((double)s, lds);
    if (tid == 0) ws->p2[blockIdx.x] = t;
}

// ---------------------------------------------------------------------------
// Kernel C: reduce p2[0..nb2) -> out (single block; kernel boundary = barrier)
// ---------------------------------------------------------------------------
__global__ __launch_bounds__(NTHR) void finalize_kernel(
    const Ws* __restrict__ ws, float* __restrict__ out, long n, int nb2) {
    __shared__ double lds[WPB];
    double m = 0.0;
    for (int k = threadIdx.x; k < nb2; k += NTHR) m += ws->p2[k];
    m = block_reduce(m, lds);
    if (threadIdx.x == 0) out[0] = (float)(m / (double)n);
}

extern "C" void kernel_launch(void* const* d_in, const int* in_sizes, int n_in,
                              void* d_out, int out_size, void* d_ws, size_t ws_size,
                              hipStream_t stream) {
    const float* sims = (const float*)d_in[0];
    const long n = (long)in_sizes[0];
    Ws* ws = (Ws*)d_ws;
    float* out = (float*)d_out;

    if (ws_size >= sizeof(Ws)) {
        sum_kernel<true><<<NBLK, NTHR, 0, stream>>>(sims, n, ws);
        loss_kernel<true><<<NB2, NTHR, 0, stream>>>(sims, n, ws);
        finalize_kernel<<<1, NTHR, 0, stream>>>(ws, out, n, NB2);
    } else {
        // classic 2-full-pass path (touches only p1/p2)
        sum_kernel<false><<<NBLK, NTHR, 0, stream>>>(sims, n, ws);
        loss_kernel<false><<<NBLK, NTHR, 0, stream>>>(sims, n, ws);
        finalize_kernel<<<1, NTHR, 0, stream>>>(ws, out, n, NBLK);
    }
}

// Round 11
// 40.257 us; speedup vs baseline: 1.2960x; 1.2960x over previous
//
#include <hip/hip_runtime.h>
#include <hip/hip_fp16.h>

#define MARGIN 0.2f
#define WINDOW 0.25f     // compact |s| < WINDOW in pass 1
#define MU_MAX 0.045     // fast path valid iff |mean| <= MU_MAX (WINDOW - MU_MAX > MARGIN)
#define NBLK 2048
#define NTHR 256
#define WPB  (NTHR / 64) // waves per block
#define WCAP 1280        // per-wave candidate capacity (expected ~809, sigma ~26)

// Lessons (R3-R5, R9, R10): NO mid-kernel __threadfence (~+220us); NO fused
// finalize via same-line atomics (~+35us); NO histogram (unexplained replay
// divergence); K2 needs max grid/TLP (512-block variant was +10us). Kernel
// boundaries are the cheap cross-block barrier; ballot-compaction is
// bit-deterministic (no atomics). Candidates half-packed: all in
// (-0.25,0.25), ulp <= 1.22e-4, final-mean error ~1e-5 << 3.17e-4 threshold.
// R11 delta vs R8: K2 candidate reads vectorized as __half2.
struct Ws {
    double   p1[NBLK];                        // per-block partial sums
    double   p2[NBLK];                        // per-block partial loss sums
    unsigned counts[NBLK * WPB];              // true per-wave candidate counts
    __half   cand[(size_t)NBLK * WPB * WCAP]; // per-wave candidate segments (~21 MB)
};

__device__ __forceinline__ double block_reduce(double v, double* lds) {
    #pragma unroll
    for (int off = 32; off > 0; off >>= 1) v += __shfl_down(v, off);
    const int w = threadIdx.x >> 6;
    if ((threadIdx.x & 63) == 0) lds[w] = v;
    __syncthreads();
    double t = 0.0;
    if (threadIdx.x == 0) {
        #pragma unroll
        for (int i = 0; i < WPB; ++i) t += lds[i];
    }
    __syncthreads();
    return t;
}

// Contiguous chunk geometry: block b owns len4 float4s starting at base4.
__device__ __forceinline__ void chunk_of(long n4, long b, long& base4, long& len4) {
    const long chunk4 = n4 / NBLK, rem4 = n4 % NBLK;
    base4 = b * chunk4 + (b < rem4 ? b : rem4);
    len4  = chunk4 + (b < rem4 ? 1 : 0);
}

// ---------------------------------------------------------------------------
// Kernel A (byte-identical to R8): per-block sum; if COMPACT, wave-ballot-
// compact |s|<WINDOW candidates (as __half) into fixed per-wave segments.
// ---------------------------------------------------------------------------
template<bool COMPACT>
__global__ __launch_bounds__(NTHR) void sum_kernel(
    const float* __restrict__ in, long n, Ws* __restrict__ ws) {
    __shared__ double lds[WPB];
    const long n4 = n >> 2;
    const float4* __restrict__ in4 = reinterpret_cast<const float4*>(in);
    long base4, len4;
    chunk_of(n4, blockIdx.x, base4, len4);
    const int tid = threadIdx.x;
    const unsigned lane =
        __builtin_amdgcn_mbcnt_hi(~0u, __builtin_amdgcn_mbcnt_lo(~0u, 0u));
    const unsigned long long below = (1ull << lane) - 1ull;

    __half* seg = nullptr;
    unsigned wbase = 0;
    if (COMPACT)
        seg = ws->cand + (size_t)(blockIdx.x * WPB + (tid >> 6)) * WCAP;

    float s = 0.0f;
    const long rounds = (len4 + NTHR - 1) / NTHR;   // wave-uniform trip count
    for (long r = 0; r < rounds; ++r) {
        const long k = r * NTHR + tid;
        const bool act = (k < len4);
        float4 v = act ? in4[base4 + k] : make_float4(0.f, 0.f, 0.f, 0.f);
        if (COMPACT) {
            const float e[4] = {v.x, v.y, v.z, v.w};
            #pragma unroll
            for (int c = 0; c < 4; ++c) {
                const bool cand = act && (fabsf(e[c]) < WINDOW);
                const unsigned long long m = __ballot(cand);
                if (cand) {
                    const unsigned off = wbase + (unsigned)__popcll(m & below);
                    if (off < WCAP) seg[off] = __float2half(e[c]);
                }
                wbase += (unsigned)__popcll(m);
            }
        }
        s += (v.x + v.y) + (v.z + v.w);
    }
    if (COMPACT && (tid & 63) == 0)
        ws->counts[blockIdx.x * WPB + (tid >> 6)] = wbase;  // TRUE count

    if (blockIdx.x == 0) {   // scalar tail (n % 4)
        for (long j = (n4 << 2) + tid; j < n; j += NTHR) s += in[j];
    }
    const double t = block_reduce((double)s, lds);
    if (tid == 0) ws->p1[blockIdx.x] = t;
}

// ---------------------------------------------------------------------------
// Kernel B: mean from p1, then loss. Fast path sums candidates only
// (__half2-vectorized); fallbacks (|mean|>MU_MAX grid-wide, or per-block
// segment overflow) rescan the block's own contiguous chunk. Exactness:
// excluded elements have |s| >= WINDOW and |mean| <= MU_MAX ->
// |s-mean| >= 0.205 > MARGIN -> loss exactly 0.
// ---------------------------------------------------------------------------
template<bool TRY_FAST>
__global__ __launch_bounds__(NTHR) void loss_kernel(
    const float* __restrict__ in, long n, Ws* __restrict__ ws) {
    __shared__ double lds[WPB];
    const int tid = threadIdx.x;

    double m = 0.0;
    for (int k = tid; k < NBLK; k += NTHR) m += ws->p1[k];
    m = block_reduce(m, lds);
    __shared__ double s_mean;
    if (tid == 0) s_mean = m / (double)n;
    __syncthreads();
    const float mean = (float)s_mean;

    const long n4 = n >> 2;
    const float4* __restrict__ in4 = reinterpret_cast<const float4*>(in);

    bool fast = false;
    if (TRY_FAST) {
        __shared__ int s_ovf;
        if (tid == 0) {
            int of = 0;
            #pragma unroll
            for (int w = 0; w < WPB; ++w)
                of |= (ws->counts[blockIdx.x * WPB + w] > WCAP) ? 1 : 0;
            s_ovf = of;
        }
        __syncthreads();
        fast = (fabs(s_mean) <= (double)MU_MAX) && (s_ovf == 0);
    }

    float s = 0.0f;
    if (fast) {
        const int wave = tid >> 6, lane = tid & 63;
        const unsigned cnt = ws->counts[blockIdx.x * WPB + wave];
        const __half* __restrict__ seg =
            ws->cand + (size_t)(blockIdx.x * WPB + wave) * WCAP;
        // Vectorized pair loads (seg is 4B-aligned: WCAP even, struct aligned)
        const __half2* __restrict__ seg2 =
            reinterpret_cast<const __half2*>(seg);
        const unsigned npair = cnt >> 1;
        for (unsigned j = lane; j < npair; j += 64) {
            const float2 f = __half22float2(seg2[j]);
            s += fmaxf(MARGIN - fabsf(f.x - mean), 0.0f)
               + fmaxf(MARGIN - fabsf(f.y - mean), 0.0f);
        }
        if ((cnt & 1u) && lane == 0)
            s += fmaxf(MARGIN - fabsf(__half2float(seg[cnt - 1]) - mean), 0.0f);
    } else {
        long base4, len4;
        chunk_of(n4, blockIdx.x, base4, len4);
        for (long k = tid; k < len4; k += NTHR) {
            float4 v = in4[base4 + k];
            s += fmaxf(MARGIN - fabsf(v.x - mean), 0.0f)
               + fmaxf(MARGIN - fabsf(v.y - mean), 0.0f);
            s += fmaxf(MARGIN - fabsf(v.z - mean), 0.0f)
               + fmaxf(MARGIN - fabsf(v.w - mean), 0.0f);
        }
    }
    if (blockIdx.x == 0) {   // scalar tail (n % 4)
        for (long j = (n4 << 2) + tid; j < n; j += NTHR)
            s += fmaxf(MARGIN - fabsf(in[j] - mean), 0.0f);
    }
    const double t = block_reduce((double)s, lds);
    if (tid == 0) ws->p2[blockIdx.x] = t;
}

// ---------------------------------------------------------------------------
// Kernel C: reduce p2 -> out (single block; kernel boundary = cheap barrier)
// ---------------------------------------------------------------------------
__global__ __launch_bounds__(NTHR) void finalize_kernel(
    const Ws* __restrict__ ws, float* __restrict__ out, long n) {
    __shared__ double lds[WPB];
    double m = 0.0;
    for (int k = threadIdx.x; k < NBLK; k += NTHR) m += ws->p2[k];
    m = block_reduce(m, lds);
    if (threadIdx.x == 0) out[0] = (float)(m / (double)n);
}

extern "C" void kernel_launch(void* const* d_in, const int* in_sizes, int n_in,
                              void* d_out, int out_size, void* d_ws, size_t ws_size,
                              hipStream_t stream) {
    const float* sims = (const float*)d_in[0];
    const long n = (long)in_sizes[0];
    Ws* ws = (Ws*)d_ws;
    float* out = (float*)d_out;

    if (ws_size >= sizeof(Ws)) {
        sum_kernel<true><<<NBLK, NTHR, 0, stream>>>(sims, n, ws);
        loss_kernel<true><<<NBLK, NTHR, 0, stream>>>(sims, n, ws);
    } else {
        // classic 2-full-pass path (touches only p1/p2)
        sum_kernel<false><<<NBLK, NTHR, 0, stream>>>(sims, n, ws);
        loss_kernel<false><<<NBLK, NTHR, 0, stream>>>(sims, n, ws);
    }
    finalize_kernel<<<1, NTHR, 0, stream>>>(ws, out, n);
}